// Round 7
// baseline (13914.134 us; speedup 1.0000x reference)
//
#include <hip/hip_runtime.h>

// R7: phase-staggered 2-item pipeline.
// Prepass xproj_mfma (unchanged from R6): xp = x·W_in^T + b_in + b_rec.
// Scan: 32 WGs x 256 thr (4 waves, 1/SIMD). Wave g owns cols [64g,64g+64)
// as 4 tiles for BOTH items A,B. W_rec B-frags stationary (AGPR-resident is
// fine: MFMA reads B from AGPRs). Items staggered by one half-layer:
//   interval it (phase = it&1): MFMA for item[phase] (reads hL[phase], LDS,
//   stride-72 conflict-free) PLUS epilogue for item[phase^1] using the acc
//   computed last interval (pure register inputs -> issues under the MFMA
//   chain's latency). One barrier per interval; h single-buffered per item
//   (never read+written in the same interval).
// R6 lockstep ran 2 items at the SAME per-layer critical path (~2100cy);
// staggering overlaps the two chains. R2 lesson enforced: phase selection
// via inlined helpers w/ array-reference params, never runtime-indexed
// local arrays.

typedef _Float16 half8 __attribute__((ext_vector_type(8)));
typedef float    f32x4 __attribute__((ext_vector_type(4)));

__device__ __forceinline__ float fast_tanh(float z) {
    float e = __expf(2.0f * z);        // inf-safe
    return 1.0f - 2.0f / (e + 1.0f);
}

__device__ __forceinline__ half8 cvt8(float4 v0, float4 v1) {
    half8 hv;
    hv[0]=(_Float16)v0.x; hv[1]=(_Float16)v0.y;
    hv[2]=(_Float16)v0.z; hv[3]=(_Float16)v0.w;
    hv[4]=(_Float16)v1.x; hv[5]=(_Float16)v1.y;
    hv[6]=(_Float16)v1.z; hv[7]=(_Float16)v1.w;
    return hv;
}

// permuted h address: k = 32i + 8q + j -> 72q + 8i + j (banks 4q+4i: clean)
__device__ __forceinline__ int hp_addr(int k) {
    return 72 * ((k >> 3) & 3) + 8 * (k >> 5) + (k & 7);
}

// ---------------- prepass: xp = x·W_in^T + b_in + b_rec ----------------
__global__ void __launch_bounds__(256, 2)
xproj_mfma(const float* __restrict__ x, const float* __restrict__ W_in,
           const float* __restrict__ b_in, const float* __restrict__ b_rec,
           float* __restrict__ xp)
{
    __shared__ _Float16 wlds[32768];   // W_in in B-frag order
    const int tid = threadIdx.x, lane = tid & 63, w = tid >> 6;
    const int n = lane & 15, q = lane >> 4;

    {   // stage W_in -> LDS (thread owns col = tid)
        const int col = tid, ct = col >> 4, cn = col & 15;
        const float* wr = W_in + col * 128;
#pragma unroll
        for (int ks = 0; ks < 4; ++ks)
#pragma unroll
            for (int qq = 0; qq < 4; ++qq) {
                float4 v0 = *(const float4*)&wr[32*ks + 8*qq];
                float4 v1 = *(const float4*)&wr[32*ks + 8*qq + 4];
                *(half8*)&wlds[(((ct*4+ks)*4+qq)*16+cn)*8] = cvt8(v0, v1);
            }
    }
    float biasv[16];
#pragma unroll
    for (int ct = 0; ct < 16; ++ct)
        biasv[ct] = b_in[16*ct + n] + b_rec[16*ct + n];
    __syncthreads();

    const int rowbase0 = blockIdx.x * 256 + w * 64;
#pragma unroll 1
    for (int rt = 0; rt < 4; ++rt) {
        const int rb = rowbase0 + rt * 16;
        half8 af[4];
#pragma unroll
        for (int ks = 0; ks < 4; ++ks) {
            const float* xr = x + (size_t)(rb + n) * 128 + 32*ks + 8*q;
            af[ks] = cvt8(*(const float4*)&xr[0], *(const float4*)&xr[4]);
        }
        f32x4 acc[16];
#pragma unroll
        for (int ct = 0; ct < 16; ++ct)
            acc[ct] = (f32x4){biasv[ct], biasv[ct], biasv[ct], biasv[ct]};
#pragma unroll
        for (int ks = 0; ks < 4; ++ks)
#pragma unroll
            for (int ct = 0; ct < 16; ++ct)
                acc[ct] = __builtin_amdgcn_mfma_f32_16x16x32_f16(
                    af[ks], *(const half8*)&wlds[(((ct*4+ks)*4+q)*16+n)*8],
                    acc[ct], 0, 0, 0);
        float* orow = xp + (size_t)(rb + 4*q) * 256 + n;
#pragma unroll
        for (int ct = 0; ct < 16; ++ct)
#pragma unroll
            for (int r = 0; r < 4; ++r)
                orow[(size_t)r * 256 + 16*ct] = acc[ct][r];
    }
}

// ---------------- staggered scan ----------------
struct ItemState {
    float xc[4], xn[4], xf[4];   // x-projection register pipeline
    float hj[4];                 // h state (f32)
    int   l, t;                  // layer/time counters (wave-uniform)
};

__device__ __forceinline__ void do_mfma(
    f32x4 (&acc)[4], const half8 (&bh)[4][8], const _Float16* hsrc,
    ItemState& st, const float* __restrict__ xrow, int q, int T, int L)
{
    half8 ah[8];
#pragma unroll
    for (int i = 0; i < 8; ++i)
        ah[i] = *(const half8*)&hsrc[72*q + 8*i];

#pragma unroll
    for (int t4 = 0; t4 < 4; ++t4)
        acc[t4] = (f32x4){st.xc[t4], st.xc[t4], st.xc[t4], st.xc[t4]};
#pragma unroll
    for (int i = 0; i < 8; ++i)
#pragma unroll
        for (int t4 = 0; t4 < 4; ++t4)
            acc[t4] = __builtin_amdgcn_mfma_f32_16x16x32_f16(
                ah[i], bh[t4][i], acc[t4], 0, 0, 0);

    if (st.l == 0) {             // issue t+2 loads (consumed ~2 steps later)
        const int tn = (st.t + 2 < T) ? st.t + 2 : T - 1;
        const float* src = xrow + (size_t)tn * 256;
#pragma unroll
        for (int t4 = 0; t4 < 4; ++t4) st.xf[t4] = src[64*0 + 0];  // overwritten below
        // real loads (per-tile columns handled by caller-passed xrow offsets)
    }
}

// epilogue for the OTHER item: tanh + state update + LDS write
__device__ __forceinline__ void do_epi(
    const f32x4 (&acc)[4], ItemState& st, _Float16* hdst,
    const float (&sj)[4], const int (&haddr)[4], int q)
{
#pragma unroll
    for (int t4 = 0; t4 < 4; ++t4) {
        float z = acc[t4][0];
        float a = fast_tanh(z);
        st.hj[t4] += sj[t4] * (a - st.hj[t4]);
    }
    if (q == 0) {
#pragma unroll
        for (int t4 = 0; t4 < 4; ++t4)
            hdst[haddr[t4]] = (_Float16)st.hj[t4];
    }
}

__global__ void __launch_bounds__(256, 1)
ltc_scan_pipe(const float* __restrict__ xp,     // [B*T,256]
              const float* __restrict__ W_rec,  // [256,256]
              const float* __restrict__ tau,    // [256]
              const int*   __restrict__ num_layers,
              float*       __restrict__ out,    // [B,256]
              int T, int B)
{
    const int tid  = threadIdx.x;
    const int lane = tid & 63;
    const int g    = tid >> 6;             // wave: cols [64g, 64g+64)
    const int n    = lane & 15;
    const int q    = lane >> 4;
    const int L    = num_layers[0];
    const int bA   = 2 * blockIdx.x;
    const int bB   = (bA + 1 < B) ? bA + 1 : bA;

    __shared__ _Float16 hL[2][288];        // [item][stride-72 perm]

    // ---- W_rec B-frags (stationary; AGPR residency is fine for MFMA) ----
    half8 bh[4][8];
    int   col4[4];
#pragma unroll
    for (int t4 = 0; t4 < 4; ++t4) {
        const int col = 64*g + 16*t4 + n;
        col4[t4] = col;
        const float* rp = &W_rec[col * 256 + 8*q];
#pragma unroll
        for (int i = 0; i < 8; ++i)
            bh[t4][i] = cvt8(*(const float4*)&rp[32*i],
                             *(const float4*)&rp[32*i + 4]);
    }

    float sj[4];
    int   haddr[4];
#pragma unroll
    for (int t4 = 0; t4 < 4; ++t4) {
        sj[t4]    = 0.1f / fminf(fmaxf(tau[col4[t4]], 0.1f), 5.0f);
        haddr[t4] = hp_addr(col4[t4]);
    }

    for (int i = tid; i < 2 * 288; i += 256)
        ((_Float16*)hL)[i] = (_Float16)0.0f;

    const float* xrA = xp + (size_t)bA * T * 256;
    const float* xrB = xp + (size_t)bB * T * 256;

    ItemState A, Bi;
#pragma unroll
    for (int t4 = 0; t4 < 4; ++t4) {
        A.hj[t4] = 0.f;  Bi.hj[t4] = 0.f;
        A.xc[t4]  = xrA[col4[t4]];
        Bi.xc[t4] = xrB[col4[t4]];
        const int t1 = (T > 1) ? 1 : 0;
        A.xn[t4]  = xrA[(size_t)t1 * 256 + col4[t4]];
        Bi.xn[t4] = xrB[(size_t)t1 * 256 + col4[t4]];
    }
    A.l = 0; A.t = 0; Bi.l = 0; Bi.t = 0;
    __syncthreads();

    f32x4 accA[4], accB[4];
    const long long NIT = 2LL * L * T;

    for (long long it = 0; it < NIT + 1; ++it) {
        const int phase = (int)(it & 1);

        if (it < NIT) {
            if (phase == 0) {
                // MFMA item A
                half8 ah[8];
#pragma unroll
                for (int i = 0; i < 8; ++i)
                    ah[i] = *(const half8*)&hL[0][72*q + 8*i];
#pragma unroll
                for (int t4 = 0; t4 < 4; ++t4)
                    accA[t4] = (f32x4){A.xc[t4], A.xc[t4], A.xc[t4], A.xc[t4]};
#pragma unroll
                for (int i = 0; i < 8; ++i)
#pragma unroll
                    for (int t4 = 0; t4 < 4; ++t4)
                        accA[t4] = __builtin_amdgcn_mfma_f32_16x16x32_f16(
                            ah[i], bh[t4][i], accA[t4], 0, 0, 0);
                if (A.l == 0) {
                    const int tn = (A.t + 2 < T) ? A.t + 2 : T - 1;
                    const float* src = xrA + (size_t)tn * 256;
#pragma unroll
                    for (int t4 = 0; t4 < 4; ++t4) A.xf[t4] = src[col4[t4]];
                }
                if (A.l == L - 1) {
#pragma unroll
                    for (int t4 = 0; t4 < 4; ++t4) {
                        A.xc[t4] = A.xn[t4]; A.xn[t4] = A.xf[t4];
                    }
                }
                if (++A.l == L) { A.l = 0; ++A.t; }
            } else {
                // MFMA item B
                half8 ah[8];
#pragma unroll
                for (int i = 0; i < 8; ++i)
                    ah[i] = *(const half8*)&hL[1][72*q + 8*i];
#pragma unroll
                for (int t4 = 0; t4 < 4; ++t4)
                    accB[t4] = (f32x4){Bi.xc[t4], Bi.xc[t4], Bi.xc[t4], Bi.xc[t4]};
#pragma unroll
                for (int i = 0; i < 8; ++i)
#pragma unroll
                    for (int t4 = 0; t4 < 4; ++t4)
                        accB[t4] = __builtin_amdgcn_mfma_f32_16x16x32_f16(
                            ah[i], bh[t4][i], accB[t4], 0, 0, 0);
                if (Bi.l == 0) {
                    const int tn = (Bi.t + 2 < T) ? Bi.t + 2 : T - 1;
                    const float* src = xrB + (size_t)tn * 256;
#pragma unroll
                    for (int t4 = 0; t4 < 4; ++t4) Bi.xf[t4] = src[col4[t4]];
                }
                if (Bi.l == L - 1) {
#pragma unroll
                    for (int t4 = 0; t4 < 4; ++t4) {
                        Bi.xc[t4] = Bi.xn[t4]; Bi.xn[t4] = Bi.xf[t4];
                    }
                }
                if (++Bi.l == L) { Bi.l = 0; ++Bi.t; }
            }
        }

        if (it > 0) {
            if (phase == 0) do_epi(accB, Bi, hL[1], sj, haddr, q);
            else            do_epi(accA, A,  hL[0], sj, haddr, q);
        }
        __syncthreads();
    }

    if (q == 0) {
#pragma unroll
        for (int t4 = 0; t4 < 4; ++t4) {
            out[(size_t)bA * 256 + col4[t4]] = A.hj[t4];
            if (bB != bA)
                out[(size_t)bB * 256 + col4[t4]] = Bi.hj[t4];
        }
    }
}

// ---------------- fallback (ws too small): R5 kernel ----------------
__device__ __forceinline__ int hp_addr64(int k) {
    return ((k >> 3) & 3) * 64 + (k >> 5) * 8 + (k & 7);
}
__device__ __forceinline__ int xp_addr32(int k) {
    return ((k >> 3) & 3) * 32 + (k >> 5) * 8 + (k & 7);
}
typedef _Float16 half4f __attribute__((ext_vector_type(4)));

__global__ void __launch_bounds__(256, 1)
ltc_scan_fb(const float* __restrict__ x, const float* __restrict__ W_in,
            const float* __restrict__ b_in, const float* __restrict__ W_rec,
            const float* __restrict__ b_rec, const float* __restrict__ tau,
            const int* __restrict__ num_layers, float* __restrict__ out, int T)
{
    const int b = blockIdx.x, tid = threadIdx.x;
    const int lane = tid & 63, w = tid >> 6;
    const int n = lane & 15, q = lane >> 4;
    const int L = num_layers[0];

    __shared__ _Float16 hperm[2][256];
    __shared__ _Float16 xperm[2][128];

    half8 bh[4][8];
#pragma unroll
    for (int t4 = 0; t4 < 4; ++t4) {
        const int col = 64*w + 16*t4 + n;
        const float* rp = &W_rec[col * 256 + 8*q];
#pragma unroll
        for (int i = 0; i < 8; ++i)
            bh[t4][i] = cvt8(*(const float4*)&rp[32*i], *(const float4*)&rp[32*i+4]);
    }
    half8 bx[4][4];
#pragma unroll
    for (int t4 = 0; t4 < 4; ++t4) {
        const int col = 64*w + 16*t4 + n;
        const float* rp = &W_in[col * 128 + 8*q];
#pragma unroll
        for (int i = 0; i < 4; ++i)
            bx[t4][i] = cvt8(*(const float4*)&rp[32*i], *(const float4*)&rp[32*i+4]);
    }
    float bias[4], sj[4], hj[4];
    int haddr[4];
#pragma unroll
    for (int t4 = 0; t4 < 4; ++t4) {
        const int col = 64*w + 16*t4 + n;
        bias[t4] = b_in[col] + b_rec[col];
        sj[t4] = 0.1f / fminf(fmaxf(tau[col], 0.1f), 5.0f);
        hj[t4] = 0.0f;
        haddr[t4] = hp_addr64(col);
    }
    if (tid < 256) hperm[0][tid] = (_Float16)0.0f;
    const float* xb = x + (size_t)b * T * 128;
    if (tid < 32) {
        float4 xfv = *(const float4*)&xb[4 * tid];
        half4f hv;
        hv[0]=(_Float16)xfv.x; hv[1]=(_Float16)xfv.y;
        hv[2]=(_Float16)xfv.z; hv[3]=(_Float16)xfv.w;
        *(half4f*)&xperm[0][xp_addr32(4 * tid)] = hv;
    }
    __syncthreads();

    int hb = 0;
    for (int t = 0; t < T; ++t) {
        const bool ldx = (tid < 32) && (t + 1 < T);
        float4 xfv;
        if (ldx) xfv = *(const float4*)&xb[(size_t)(t + 1) * 128 + 4 * tid];

        f32x4 px[4];
#pragma unroll
        for (int t4 = 0; t4 < 4; ++t4)
            px[t4] = (f32x4){bias[t4], bias[t4], bias[t4], bias[t4]};
        {
            const _Float16* xsrc = &xperm[t & 1][q * 32];
            half8 ax[4];
#pragma unroll
            for (int i = 0; i < 4; ++i) ax[i] = *(const half8*)&xsrc[8 * i];
#pragma unroll
            for (int i = 0; i < 4; ++i)
#pragma unroll
                for (int t4 = 0; t4 < 4; ++t4)
                    px[t4] = __builtin_amdgcn_mfma_f32_16x16x32_f16(
                        ax[i], bx[t4][i], px[t4], 0, 0, 0);
        }
        for (int l = 0; l < L; ++l) {
            f32x4 acc[4];
#pragma unroll
            for (int t4 = 0; t4 < 4; ++t4) acc[t4] = px[t4];
            const _Float16* hsrc = &hperm[hb][q * 64];
            half8 ah[8];
#pragma unroll
            for (int i = 0; i < 8; ++i) ah[i] = *(const half8*)&hsrc[8 * i];
#pragma unroll
            for (int i = 0; i < 8; ++i)
#pragma unroll
                for (int t4 = 0; t4 < 4; ++t4)
                    acc[t4] = __builtin_amdgcn_mfma_f32_16x16x32_f16(
                        ah[i], bh[t4][i], acc[t4], 0, 0, 0);
#pragma unroll
            for (int t4 = 0; t4 < 4; ++t4) {
                float z = acc[t4][0];
                float a = fast_tanh(z);
                hj[t4] += sj[t4] * (a - hj[t4]);
            }
            if (q == 0) {
#pragma unroll
                for (int t4 = 0; t4 < 4; ++t4)
                    hperm[hb ^ 1][haddr[t4]] = (_Float16)hj[t4];
            }
            if (l == L - 1 && ldx) {
                half4f hv;
                hv[0]=(_Float16)xfv.x; hv[1]=(_Float16)xfv.y;
                hv[2]=(_Float16)xfv.z; hv[3]=(_Float16)xfv.w;
                *(half4f*)&xperm[(t + 1) & 1][xp_addr32(4 * tid)] = hv;
            }
            __syncthreads();
            hb ^= 1;
        }
    }
    if (q == 0) {
#pragma unroll
        for (int t4 = 0; t4 < 4; ++t4)
            out[(size_t)b * 256 + 64*w + 16*t4 + n] = hj[t4];
    }
}

extern "C" void kernel_launch(void* const* d_in, const int* in_sizes, int n_in,
                              void* d_out, int out_size, void* d_ws, size_t ws_size,
                              hipStream_t stream) {
    const float* x     = (const float*)d_in[0];
    const float* W_in  = (const float*)d_in[1];
    const float* b_in  = (const float*)d_in[2];
    const float* W_rec = (const float*)d_in[3];
    const float* b_rec = (const float*)d_in[4];
    const float* tau   = (const float*)d_in[5];
    const int*   numl  = (const int*)d_in[6];

    const int H = in_sizes[2];            // 256
    const int I = in_sizes[1] / H;        // 128
    const int B = out_size / H;           // 64
    const int T = in_sizes[0] / (B * I);  // 4096
    const size_t xp_bytes = (size_t)B * T * H * sizeof(float);

    if (ws_size >= xp_bytes && ((B * T) % 256) == 0) {
        float* xp = (float*)d_ws;
        xproj_mfma<<<(B * T) / 256, 256, 0, stream>>>(x, W_in, b_in, b_rec, xp);
        ltc_scan_pipe<<<(B + 1) / 2, 256, 0, stream>>>(xp, W_rec, tau, numl,
                                                       (float*)d_out, T, B);
    } else {
        ltc_scan_fb<<<B, 256, 0, stream>>>(x, W_in, b_in, W_rec, b_rec, tau,
                                           numl, (float*)d_out, T);
    }
}

// Round 8
// 5205.666 us; speedup vs baseline: 2.6729x; 2.6729x over previous
//
#include <hip/hip_runtime.h>

// R8: fully-fused single kernel. 64 WGs (1 item each) x 256 thr (4 waves,
// 1/SIMD). Wave g owns out-cols [64g,64g+64) as 4 16-col tiles.
//
// Measured lesson (R5-R7): every barrier interval costs ~2000cy, ~1100 of
// which is the __syncthreads vmcnt(0) drain of in-flight global xp loads
// (guide: barrier semantics drain ALL outstanding loads). Fix: ZERO global
// loads in the steady loop. Every 32 steps, a staging phase: load x chunk
// (4x b128/thread, ONE drain per 32 t), MFMA-project it (K=128, acc seeded
// with b_in+b_rec), park proj in LDS (f16). Steady interval touches only
// LDS: xc b64 broadcast + 8x b128 h (stride-72, verified conflict-free) +
// 32 MFMA (two 4-chains) + 4 tanh + b16 h write + 1 barrier/layer.
// W_rec/W_in B-frags stationary in regs (AGPR-resident OK for MFMA).
// h state f32 in regs; only MFMA inputs are f16 (absmax ~0.004 in R5-R7).

typedef _Float16 half8 __attribute__((ext_vector_type(8)));
typedef _Float16 half4 __attribute__((ext_vector_type(4)));
typedef float    f32x4 __attribute__((ext_vector_type(4)));

__device__ __forceinline__ float fast_tanh(float z) {
    float e = __expf(2.0f * z);        // inf-safe
    return 1.0f - 2.0f / (e + 1.0f);
}

__device__ __forceinline__ half8 cvt8(float4 v0, float4 v1) {
    half8 hv;
    hv[0]=(_Float16)v0.x; hv[1]=(_Float16)v0.y;
    hv[2]=(_Float16)v0.z; hv[3]=(_Float16)v0.w;
    hv[4]=(_Float16)v1.x; hv[5]=(_Float16)v1.y;
    hv[6]=(_Float16)v1.z; hv[7]=(_Float16)v1.w;
    return hv;
}
__device__ __forceinline__ half4 cvt4(float4 v) {
    half4 hv;
    hv[0]=(_Float16)v.x; hv[1]=(_Float16)v.y;
    hv[2]=(_Float16)v.z; hv[3]=(_Float16)v.w;
    return hv;
}

// permuted h address: k = 32i + 8q + j -> 72q + 8i + j (banks 4q+4i: clean)
__device__ __forceinline__ int hp_addr(int k) {
    return 72 * ((k >> 3) & 3) + 8 * (k >> 5) + (k & 7);
}

__global__ void __launch_bounds__(256, 1)
ltc_fused(const float* __restrict__ x,      // [B,T,128]
          const float* __restrict__ W_in,   // [256,128]
          const float* __restrict__ b_in,   // [256]
          const float* __restrict__ W_rec,  // [256,256]
          const float* __restrict__ b_rec,  // [256]
          const float* __restrict__ tau,    // [256]
          const int*   __restrict__ num_layers,
          float*       __restrict__ out,    // [B,256]
          int T)
{
    const int b    = blockIdx.x;
    const int tid  = threadIdx.x;
    const int lane = tid & 63;
    const int g    = tid >> 6;             // wave: out-cols [64g, 64g+64)
    const int n    = lane & 15;
    const int q    = lane >> 4;
    const int L    = num_layers[0];

    __shared__ _Float16 hperm[2][288];          // h, stride-72 perm, dbuf
    __shared__ _Float16 xstage[2][16][16][8];   // x chunk, A-frag order, 8KB
    __shared__ _Float16 pchunk[32][4][16][4];   // proj chunk, 16KB

    // ---- stationary B-frags: W_rec (4x8) + W_in (4x4), f16 ----
    half8 bh[4][8];
    half8 bx[4][4];
    int   col4[4];
    float bias4[4], sj[4], hj4[4];
    int   haddr[4];
#pragma unroll
    for (int t4 = 0; t4 < 4; ++t4) {
        const int col = 64*g + 16*t4 + n;
        col4[t4] = col;
        const float* rp = &W_rec[col * 256 + 8*q];
#pragma unroll
        for (int i = 0; i < 8; ++i)
            bh[t4][i] = cvt8(*(const float4*)&rp[32*i],
                             *(const float4*)&rp[32*i + 4]);
        const float* ip = &W_in[col * 128 + 8*q];
#pragma unroll
        for (int i = 0; i < 4; ++i)
            bx[t4][i] = cvt8(*(const float4*)&ip[32*i],
                             *(const float4*)&ip[32*i + 4]);
        bias4[t4] = b_in[col] + b_rec[col];
        sj[t4]    = 0.1f / fminf(fmaxf(tau[col], 0.1f), 5.0f);
        hj4[t4]   = 0.0f;
        haddr[t4] = hp_addr(col);
    }

    for (int i = tid; i < 2 * 288; i += 256)
        ((_Float16*)hperm)[i] = (_Float16)0.0f;
    // (first-use barrier provided by the staging barriers below)

    const float* xb  = x + (size_t)b * T * 128;
    const int    t_u = tid >> 3;           // staging: this thread's timestep
    const int    c8  = tid & 7;            // staging: 16-f32 block index
    const int    Mts = t_u >> 4, ms = t_u & 15;

    int hb = 0;
    for (int tc = 0; tc < T; tc += 32) {
        // ---- stage x chunk (the ONLY global loads; one drain per 32 t) ----
        {
            int tg = tc + t_u; if (tg > T - 1) tg = T - 1;
            const float4* src = (const float4*)(xb + (size_t)tg * 128 + 16*c8);
            float4 v0 = src[0], v1 = src[1], v2 = src[2], v3 = src[3];
            *(half4*)&xstage[Mts][2*c8    ][ms][0] = cvt4(v0);
            *(half4*)&xstage[Mts][2*c8    ][ms][4] = cvt4(v1);
            *(half4*)&xstage[Mts][2*c8 + 1][ms][0] = cvt4(v2);
            *(half4*)&xstage[Mts][2*c8 + 1][ms][4] = cvt4(v3);
        }
        __syncthreads();

        // ---- project chunk: proj = x·W_in^T + b_in + b_rec (M=timesteps) ----
#pragma unroll
        for (int Mt = 0; Mt < 2; ++Mt) {
            half8 ax[4];
#pragma unroll
            for (int ks = 0; ks < 4; ++ks)
                ax[ks] = *(const half8*)&xstage[Mt][4*ks + q][n][0];
            f32x4 pa[4];
#pragma unroll
            for (int t4 = 0; t4 < 4; ++t4)
                pa[t4] = (f32x4){bias4[t4], bias4[t4], bias4[t4], bias4[t4]};
#pragma unroll
            for (int ks = 0; ks < 4; ++ks)
#pragma unroll
                for (int t4 = 0; t4 < 4; ++t4)
                    pa[t4] = __builtin_amdgcn_mfma_f32_16x16x32_f16(
                        ax[ks], bx[t4][ks], pa[t4], 0, 0, 0);
            // D: row = timestep 16Mt+4q+r, col = col4[t4]
#pragma unroll
            for (int r = 0; r < 4; ++r) {
                half4 pk;
                pk[0] = (_Float16)pa[0][r]; pk[1] = (_Float16)pa[1][r];
                pk[2] = (_Float16)pa[2][r]; pk[3] = (_Float16)pa[3][r];
                *(half4*)&pchunk[16*Mt + 4*q + r][g][n][0] = pk;
            }
        }
        __syncthreads();

        // ---- steady scan: LDS-only intervals ----
        const int tlen = (T - tc < 32) ? (T - tc) : 32;
        for (int ts = 0; ts < tlen; ++ts) {
            half4 xv = *(const half4*)&pchunk[ts][g][n][0];
            float xcf[4];
#pragma unroll
            for (int t4 = 0; t4 < 4; ++t4) xcf[t4] = (float)xv[t4];

            for (int l = 0; l < L; ++l) {
                half8 ah[8];
#pragma unroll
                for (int i = 0; i < 8; ++i)
                    ah[i] = *(const half8*)&hperm[hb][72*q + 8*i];

                f32x4 a0[4], a1[4];
#pragma unroll
                for (int t4 = 0; t4 < 4; ++t4) {
                    a0[t4] = (f32x4){xcf[t4], xcf[t4], xcf[t4], xcf[t4]};
                    a1[t4] = (f32x4){0.f, 0.f, 0.f, 0.f};
                }
#pragma unroll
                for (int i = 0; i < 4; ++i)
#pragma unroll
                    for (int t4 = 0; t4 < 4; ++t4)
                        a0[t4] = __builtin_amdgcn_mfma_f32_16x16x32_f16(
                            ah[i], bh[t4][i], a0[t4], 0, 0, 0);
#pragma unroll
                for (int i = 4; i < 8; ++i)
#pragma unroll
                    for (int t4 = 0; t4 < 4; ++t4)
                        a1[t4] = __builtin_amdgcn_mfma_f32_16x16x32_f16(
                            ah[i], bh[t4][i], a1[t4], 0, 0, 0);

                // epilogue (rows identical -> comp 0); h state stays f32
#pragma unroll
                for (int t4 = 0; t4 < 4; ++t4) {
                    float z = a0[t4][0] + a1[t4][0];
                    float a = fast_tanh(z);
                    hj4[t4] += sj[t4] * (a - hj4[t4]);
                }
                if (q == 0) {
#pragma unroll
                    for (int t4 = 0; t4 < 4; ++t4)
                        hperm[hb ^ 1][haddr[t4]] = (_Float16)hj4[t4];
                }
                __syncthreads();
                hb ^= 1;
            }
        }
    }

    if (q == 0) {
#pragma unroll
        for (int t4 = 0; t4 < 4; ++t4)
            out[(size_t)b * 256 + col4[t4]] = hj4[t4];
    }
}

extern "C" void kernel_launch(void* const* d_in, const int* in_sizes, int n_in,
                              void* d_out, int out_size, void* d_ws, size_t ws_size,
                              hipStream_t stream) {
    const float* x     = (const float*)d_in[0];
    const float* W_in  = (const float*)d_in[1];
    const float* b_in  = (const float*)d_in[2];
    const float* W_rec = (const float*)d_in[3];
    const float* b_rec = (const float*)d_in[4];
    const float* tau   = (const float*)d_in[5];
    const int*   numl  = (const int*)d_in[6];

    const int H = in_sizes[2];            // 256
    const int I = in_sizes[1] / H;        // 128
    const int B = out_size / H;           // 64
    const int T = in_sizes[0] / (B * I);  // 4096

    ltc_fused<<<B, 256, 0, stream>>>(x, W_in, b_in, W_rec, b_rec, tau,
                                     numl, (float*)d_out, T);
}

// Round 9
// 4170.364 us; speedup vs baseline: 3.3364x; 1.2483x over previous
//
#include <hip/hip_runtime.h>

// R9: R8 skeleton + interval-critical-path micro-optimizations.
// 64 WGs (1 item/CU) x 256 thr (4 waves, 1/SIMD). Wave g owns cols
// [64g,64g+64) as 4 16-col MFMA tiles; lane (n=lane&15, q=lane>>4).
//
// Measured chain (R5->R8): interval cost ~1450cy, content-insensitive (R6),
// latency/sync-bound. This round:
//  - steady-loop barriers are lgkm-only (raw asm) -> no vmcnt drains ever;
//  - next x-chunk prefetched into REGISTERS right after proj phase, flies
//    across all 64 steady barriers, consumed at next chunk top;
//  - epilogue split across q: lane owns col 64g+16q+n -> 6 cndmask +
//    1 tanh + scalar h + single b16 write (all lanes, no divergence);
//  - h stored PLAIN (h[c] at idx c): ah b128 reads at 16B*(4i+q) -> banks
//    4q+16i, n-broadcast, conflict-free; writes 2-way (free).
// h state f32 in regs (lane's own col); MFMA inputs f16 (absmax ~0.004).

typedef _Float16 half8 __attribute__((ext_vector_type(8)));
typedef _Float16 half4 __attribute__((ext_vector_type(4)));
typedef float    f32x4 __attribute__((ext_vector_type(4)));

#define LGKM_BARRIER() asm volatile("s_waitcnt lgkmcnt(0)\n\ts_barrier" ::: "memory")

__device__ __forceinline__ float fast_tanh(float z) {
    float e = __expf(2.0f * z);        // inf-safe
    return 1.0f - 2.0f / (e + 1.0f);
}

__device__ __forceinline__ half8 cvt8(float4 v0, float4 v1) {
    half8 hv;
    hv[0]=(_Float16)v0.x; hv[1]=(_Float16)v0.y;
    hv[2]=(_Float16)v0.z; hv[3]=(_Float16)v0.w;
    hv[4]=(_Float16)v1.x; hv[5]=(_Float16)v1.y;
    hv[6]=(_Float16)v1.z; hv[7]=(_Float16)v1.w;
    return hv;
}
__device__ __forceinline__ half4 cvt4(float4 v) {
    half4 hv;
    hv[0]=(_Float16)v.x; hv[1]=(_Float16)v.y;
    hv[2]=(_Float16)v.z; hv[3]=(_Float16)v.w;
    return hv;
}

// select a[q][0] without dynamic indexing (3 cndmask)
__device__ __forceinline__ float sel4(const f32x4 (&a)[4], int q) {
    float v0 = (q & 2) ? a[2][0] : a[0][0];
    float v1 = (q & 2) ? a[3][0] : a[1][0];
    return (q & 1) ? v1 : v0;
}

__global__ void __launch_bounds__(256, 1)
ltc_fused(const float* __restrict__ x,      // [B,T,128]
          const float* __restrict__ W_in,   // [256,128]
          const float* __restrict__ b_in,   // [256]
          const float* __restrict__ W_rec,  // [256,256]
          const float* __restrict__ b_rec,  // [256]
          const float* __restrict__ tau,    // [256]
          const int*   __restrict__ num_layers,
          float*       __restrict__ out,    // [B,256]
          int T)
{
    const int b    = blockIdx.x;
    const int tid  = threadIdx.x;
    const int lane = tid & 63;
    const int g    = tid >> 6;             // wave: out-cols [64g, 64g+64)
    const int n    = lane & 15;
    const int q    = lane >> 4;
    const int L    = num_layers[0];
    const int mycol = 64*g + 16*q + n;     // this lane's epilogue column

    __shared__ _Float16 hbuf[2][256];           // h, PLAIN layout, dbuf
    __shared__ _Float16 xstage[2][16][16][8];   // x chunk, A-frag order
    __shared__ _Float16 pchunk[32][4][16][4];   // proj chunk [ts][g][n][t4]

    // ---- stationary B-frags: W_rec (4x8) + W_in (4x4), f16 ----
    half8 bh[4][8];
    half8 bx[4][4];
    float biasv[4];
#pragma unroll
    for (int t4 = 0; t4 < 4; ++t4) {
        const int col = 64*g + 16*t4 + n;
        const float* rp = &W_rec[col * 256 + 8*q];
#pragma unroll
        for (int i = 0; i < 8; ++i)
            bh[t4][i] = cvt8(*(const float4*)&rp[32*i],
                             *(const float4*)&rp[32*i + 4]);
        const float* ip = &W_in[col * 128 + 8*q];
#pragma unroll
        for (int i = 0; i < 4; ++i)
            bx[t4][i] = cvt8(*(const float4*)&ip[32*i],
                             *(const float4*)&ip[32*i + 4]);
        biasv[t4] = b_in[col] + b_rec[col];
    }
    const float sj = 0.1f / fminf(fmaxf(tau[mycol], 0.1f), 5.0f);
    float hj = 0.0f;

    hbuf[0][tid] = (_Float16)0.0f;         // zero h buffer 0 (256 thr)

    const float* xb  = x + (size_t)b * T * 128;
    const int    t_u = tid >> 3;           // staging: timestep in chunk
    const int    c8  = tid & 7;            // staging: 16-f32 block index
    const int    Mts = t_u >> 4, ms = t_u & 15;

    // ---- chunk-0 prefetch into registers ----
    float4 xpre0, xpre1, xpre2, xpre3;
    {
        int tg = t_u; if (tg > T - 1) tg = T - 1;
        const float4* src = (const float4*)(xb + (size_t)tg * 128 + 16*c8);
        xpre0 = src[0]; xpre1 = src[1]; xpre2 = src[2]; xpre3 = src[3];
    }

    int hb = 0;
    for (int tc = 0; tc < T; tc += 32) {
        // ---- stage chunk from regs (vmcnt wait folds in here) ----
        *(half4*)&xstage[Mts][2*c8    ][ms][0] = cvt4(xpre0);
        *(half4*)&xstage[Mts][2*c8    ][ms][4] = cvt4(xpre1);
        *(half4*)&xstage[Mts][2*c8 + 1][ms][0] = cvt4(xpre2);
        *(half4*)&xstage[Mts][2*c8 + 1][ms][4] = cvt4(xpre3);
        __syncthreads();

        // ---- project chunk: proj = x·W_in^T + b_in + b_rec ----
#pragma unroll
        for (int Mt = 0; Mt < 2; ++Mt) {
            half8 ax[4];
#pragma unroll
            for (int ks = 0; ks < 4; ++ks)
                ax[ks] = *(const half8*)&xstage[Mt][4*ks + q][n][0];
            f32x4 pa[4];
#pragma unroll
            for (int t4 = 0; t4 < 4; ++t4)
                pa[t4] = (f32x4){biasv[t4], biasv[t4], biasv[t4], biasv[t4]};
#pragma unroll
            for (int ks = 0; ks < 4; ++ks)
#pragma unroll
                for (int t4 = 0; t4 < 4; ++t4)
                    pa[t4] = __builtin_amdgcn_mfma_f32_16x16x32_f16(
                        ax[ks], bx[t4][ks], pa[t4], 0, 0, 0);
#pragma unroll
            for (int r = 0; r < 4; ++r) {
                half4 pk;
                pk[0] = (_Float16)pa[0][r]; pk[1] = (_Float16)pa[1][r];
                pk[2] = (_Float16)pa[2][r]; pk[3] = (_Float16)pa[3][r];
                *(half4*)&pchunk[16*Mt + 4*q + r][g][n][0] = pk;
            }
        }
        __syncthreads();

        // ---- issue next chunk's loads NOW; they fly across the steady
        //      loop's lgkm-only barriers (no vmcnt drain anywhere) ----
        {
            const int nc = (tc + 32 < T) ? tc + 32 : tc;
            int tg = nc + t_u; if (tg > T - 1) tg = T - 1;
            const float4* src = (const float4*)(xb + (size_t)tg * 128 + 16*c8);
            xpre0 = src[0]; xpre1 = src[1]; xpre2 = src[2]; xpre3 = src[3];
        }

        // ---- steady scan: LDS-only, lgkm-barriers only ----
        const int tlen = (T - tc < 32) ? (T - tc) : 32;
        for (int ts = 0; ts < tlen; ++ts) {
            half4 xv = *(const half4*)&pchunk[ts][g][n][0];
            float xc[4];
#pragma unroll
            for (int t4 = 0; t4 < 4; ++t4) xc[t4] = (float)xv[t4];

            for (int l = 0; l < L; ++l) {
                half8 ah[8];
#pragma unroll
                for (int i = 0; i < 8; ++i)
                    ah[i] = *(const half8*)&hbuf[hb][32*i + 8*q];

                f32x4 a0[4], a1[4];
#pragma unroll
                for (int t4 = 0; t4 < 4; ++t4) {
                    a0[t4] = (f32x4){xc[t4], xc[t4], xc[t4], xc[t4]};
                    a1[t4] = (f32x4){0.f, 0.f, 0.f, 0.f};
                }
#pragma unroll
                for (int i = 0; i < 4; ++i)
#pragma unroll
                    for (int t4 = 0; t4 < 4; ++t4)
                        a0[t4] = __builtin_amdgcn_mfma_f32_16x16x32_f16(
                            ah[i], bh[t4][i], a0[t4], 0, 0, 0);
#pragma unroll
                for (int i = 4; i < 8; ++i)
#pragma unroll
                    for (int t4 = 0; t4 < 4; ++t4)
                        a1[t4] = __builtin_amdgcn_mfma_f32_16x16x32_f16(
                            ah[i], bh[t4][i], a1[t4], 0, 0, 0);

                // q-split epilogue: this lane finalizes ONLY col mycol
                float z = sel4(a0, q) + sel4(a1, q);
                float a = fast_tanh(z);
                hj += sj * (a - hj);
                hbuf[hb ^ 1][mycol] = (_Float16)hj;
                LGKM_BARRIER();
                hb ^= 1;
            }
        }
    }

    out[(size_t)b * 256 + mycol] = hj;
}

extern "C" void kernel_launch(void* const* d_in, const int* in_sizes, int n_in,
                              void* d_out, int out_size, void* d_ws, size_t ws_size,
                              hipStream_t stream) {
    const float* x     = (const float*)d_in[0];
    const float* W_in  = (const float*)d_in[1];
    const float* b_in  = (const float*)d_in[2];
    const float* W_rec = (const float*)d_in[3];
    const float* b_rec = (const float*)d_in[4];
    const float* tau   = (const float*)d_in[5];
    const int*   numl  = (const int*)d_in[6];

    const int H = in_sizes[2];            // 256
    const int I = in_sizes[1] / H;        // 128
    const int B = out_size / H;           // 64
    const int T = in_sizes[0] / (B * I);  // 4096

    ltc_fused<<<B, 256, 0, stream>>>(x, W_in, b_in, W_rec, b_rec, tau,
                                     numl, (float*)d_out, T);
}

// Round 10
// 3488.010 us; speedup vs baseline: 3.9891x; 1.1956x over previous
//
#include <hip/hip_runtime.h>

// R10: R9 structure + interval-critical-path shavings.
// 64 WGs (1 item/CU) x 256 thr (4 waves, 1/SIMD). Wave g owns cols
// [64g,64g+64) as 4 16-col MFMA tiles; lane (n=lane&15, q=lane>>4) owns
// col 64g+16q+n at the epilogue.
//
// Interval budget (measured R9 ~1190cy): DS-pipe 32xb128 ~384, MFMA tail
// ~150, tanh chain, barrier ~150. This round removes:
//  - precise f32 divide in tanh (div_scale/fmas chain ~60-80cy) -> v_rcp:
//      r = rcp(e+1); h' = fma(-2s, r, term1), term1 = fma(s,1-h,h)
//      computed BEFORE z exists (off critical path). Inf-safe both ends.
//  - per-t pchunk read latency: xc prefetched one timestep ahead into regs
//    (issued with the ah read batch at l==0).
//  - MFMA chain depth 4 -> 2 (4 chains x 4 tiles = 16 streams).
// Steady loop: LDS-only + lgkm-only barriers (no vmcnt drains; x chunk
// prefetched to regs and flies across all 64 steady barriers).

typedef _Float16 half8 __attribute__((ext_vector_type(8)));
typedef _Float16 half4 __attribute__((ext_vector_type(4)));
typedef float    f32x4 __attribute__((ext_vector_type(4)));

#define LGKM_BARRIER() asm volatile("s_waitcnt lgkmcnt(0)\n\ts_barrier" ::: "memory")

__device__ __forceinline__ half8 cvt8(float4 v0, float4 v1) {
    half8 hv;
    hv[0]=(_Float16)v0.x; hv[1]=(_Float16)v0.y;
    hv[2]=(_Float16)v0.z; hv[3]=(_Float16)v0.w;
    hv[4]=(_Float16)v1.x; hv[5]=(_Float16)v1.y;
    hv[6]=(_Float16)v1.z; hv[7]=(_Float16)v1.w;
    return hv;
}
__device__ __forceinline__ half4 cvt4(float4 v) {
    half4 hv;
    hv[0]=(_Float16)v.x; hv[1]=(_Float16)v.y;
    hv[2]=(_Float16)v.z; hv[3]=(_Float16)v.w;
    return hv;
}

// select a[q][0] without dynamic indexing (3 cndmask)
__device__ __forceinline__ float sel4(const f32x4 (&a)[4], int q) {
    float v0 = (q & 2) ? a[2][0] : a[0][0];
    float v1 = (q & 2) ? a[3][0] : a[1][0];
    return (q & 1) ? v1 : v0;
}

__global__ void __launch_bounds__(256, 1)
ltc_fused(const float* __restrict__ x,      // [B,T,128]
          const float* __restrict__ W_in,   // [256,128]
          const float* __restrict__ b_in,   // [256]
          const float* __restrict__ W_rec,  // [256,256]
          const float* __restrict__ b_rec,  // [256]
          const float* __restrict__ tau,    // [256]
          const int*   __restrict__ num_layers,
          float*       __restrict__ out,    // [B,256]
          int T)
{
    const int b    = blockIdx.x;
    const int tid  = threadIdx.x;
    const int lane = tid & 63;
    const int g    = tid >> 6;             // wave: out-cols [64g, 64g+64)
    const int n    = lane & 15;
    const int q    = lane >> 4;
    const int L    = num_layers[0];
    const int mycol = 64*g + 16*q + n;     // this lane's epilogue column

    __shared__ _Float16 hbuf[2][256];           // h, PLAIN layout, dbuf
    __shared__ _Float16 xstage[2][16][16][8];   // x chunk, A-frag order
    __shared__ _Float16 pchunk[32][4][16][4];   // proj chunk [ts][g][n][t4]

    // ---- stationary B-frags: W_rec (4x8) + W_in (4x4), f16 ----
    half8 bh[4][8];
    half8 bx[4][4];
    float biasv[4];
#pragma unroll
    for (int t4 = 0; t4 < 4; ++t4) {
        const int col = 64*g + 16*t4 + n;
        const float* rp = &W_rec[col * 256 + 8*q];
#pragma unroll
        for (int i = 0; i < 8; ++i)
            bh[t4][i] = cvt8(*(const float4*)&rp[32*i],
                             *(const float4*)&rp[32*i + 4]);
        const float* ip = &W_in[col * 128 + 8*q];
#pragma unroll
        for (int i = 0; i < 4; ++i)
            bx[t4][i] = cvt8(*(const float4*)&ip[32*i],
                             *(const float4*)&ip[32*i + 4]);
        biasv[t4] = b_in[col] + b_rec[col];
    }
    const float sj   = 0.1f / fminf(fmaxf(tau[mycol], 0.1f), 5.0f);
    const float nsj2 = -2.0f * sj;
    float hj = 0.0f;

    hbuf[0][tid] = (_Float16)0.0f;         // zero h buffer 0 (256 thr)

    const float* xb  = x + (size_t)b * T * 128;
    const int    t_u = tid >> 3;           // staging: timestep in chunk
    const int    c8  = tid & 7;            // staging: 16-f32 block index
    const int    Mts = t_u >> 4, ms = t_u & 15;

    // ---- chunk-0 prefetch into registers ----
    float4 xpre0, xpre1, xpre2, xpre3;
    {
        int tg = t_u; if (tg > T - 1) tg = T - 1;
        const float4* src = (const float4*)(xb + (size_t)tg * 128 + 16*c8);
        xpre0 = src[0]; xpre1 = src[1]; xpre2 = src[2]; xpre3 = src[3];
    }

    int hb = 0;
    for (int tc = 0; tc < T; tc += 32) {
        // ---- stage chunk from regs (vmcnt wait folds in here) ----
        *(half4*)&xstage[Mts][2*c8    ][ms][0] = cvt4(xpre0);
        *(half4*)&xstage[Mts][2*c8    ][ms][4] = cvt4(xpre1);
        *(half4*)&xstage[Mts][2*c8 + 1][ms][0] = cvt4(xpre2);
        *(half4*)&xstage[Mts][2*c8 + 1][ms][4] = cvt4(xpre3);
        __syncthreads();

        // ---- project chunk: proj = x·W_in^T + b_in + b_rec ----
#pragma unroll
        for (int Mt = 0; Mt < 2; ++Mt) {
            half8 ax[4];
#pragma unroll
            for (int ks = 0; ks < 4; ++ks)
                ax[ks] = *(const half8*)&xstage[Mt][4*ks + q][n][0];
            f32x4 pa[4];
#pragma unroll
            for (int t4 = 0; t4 < 4; ++t4)
                pa[t4] = (f32x4){biasv[t4], biasv[t4], biasv[t4], biasv[t4]};
#pragma unroll
            for (int ks = 0; ks < 4; ++ks)
#pragma unroll
                for (int t4 = 0; t4 < 4; ++t4)
                    pa[t4] = __builtin_amdgcn_mfma_f32_16x16x32_f16(
                        ax[ks], bx[t4][ks], pa[t4], 0, 0, 0);
#pragma unroll
            for (int r = 0; r < 4; ++r) {
                half4 pk;
                pk[0] = (_Float16)pa[0][r]; pk[1] = (_Float16)pa[1][r];
                pk[2] = (_Float16)pa[2][r]; pk[3] = (_Float16)pa[3][r];
                *(half4*)&pchunk[16*Mt + 4*q + r][g][n][0] = pk;
            }
        }
        __syncthreads();

        // ---- issue next chunk's global loads; fly across lgkm barriers ----
        {
            const int nc = (tc + 32 < T) ? tc + 32 : tc;
            int tg = nc + t_u; if (tg > T - 1) tg = T - 1;
            const float4* src = (const float4*)(xb + (size_t)tg * 128 + 16*c8);
            xpre0 = src[0]; xpre1 = src[1]; xpre2 = src[2]; xpre3 = src[3];
        }

        // ---- steady scan: LDS-only, lgkm-barriers only ----
        const int tlen = (T - tc < 32) ? (T - tc) : 32;
        half4 xv_cur = *(const half4*)&pchunk[0][g][n][0];   // ts=0 xc
        for (int ts = 0; ts < tlen; ++ts) {
            float xc[4];
#pragma unroll
            for (int t4 = 0; t4 < 4; ++t4) xc[t4] = (float)xv_cur[t4];
            half4 xv_nxt = xv_cur;

            for (int l = 0; l < L; ++l) {
                half8 ah[8];
#pragma unroll
                for (int i = 0; i < 8; ++i)
                    ah[i] = *(const half8*)&hbuf[hb][32*i + 8*q];
                if (l == 0) {
                    const int tsn = (ts + 1 < tlen) ? ts + 1 : ts;
                    xv_nxt = *(const half4*)&pchunk[tsn][g][n][0];
                }

                // term1 = h + s*(1-h): off critical path (needs only hj)
                const float term1 = __builtin_fmaf(sj, 1.0f - hj, hj);

                f32x4 A0[4], A1[4], A2[4], A3[4];
#pragma unroll
                for (int t4 = 0; t4 < 4; ++t4) {
                    A0[t4] = (f32x4){xc[t4], xc[t4], xc[t4], xc[t4]};
                    A1[t4] = (f32x4){0.f, 0.f, 0.f, 0.f};
                    A2[t4] = (f32x4){0.f, 0.f, 0.f, 0.f};
                    A3[t4] = (f32x4){0.f, 0.f, 0.f, 0.f};
                }
#pragma unroll
                for (int t4 = 0; t4 < 4; ++t4) {
                    A0[t4] = __builtin_amdgcn_mfma_f32_16x16x32_f16(
                        ah[0], bh[t4][0], A0[t4], 0, 0, 0);
                    A1[t4] = __builtin_amdgcn_mfma_f32_16x16x32_f16(
                        ah[2], bh[t4][2], A1[t4], 0, 0, 0);
                    A2[t4] = __builtin_amdgcn_mfma_f32_16x16x32_f16(
                        ah[4], bh[t4][4], A2[t4], 0, 0, 0);
                    A3[t4] = __builtin_amdgcn_mfma_f32_16x16x32_f16(
                        ah[6], bh[t4][6], A3[t4], 0, 0, 0);
                }
#pragma unroll
                for (int t4 = 0; t4 < 4; ++t4) {
                    A0[t4] = __builtin_amdgcn_mfma_f32_16x16x32_f16(
                        ah[1], bh[t4][1], A0[t4], 0, 0, 0);
                    A1[t4] = __builtin_amdgcn_mfma_f32_16x16x32_f16(
                        ah[3], bh[t4][3], A1[t4], 0, 0, 0);
                    A2[t4] = __builtin_amdgcn_mfma_f32_16x16x32_f16(
                        ah[5], bh[t4][5], A2[t4], 0, 0, 0);
                    A3[t4] = __builtin_amdgcn_mfma_f32_16x16x32_f16(
                        ah[7], bh[t4][7], A3[t4], 0, 0, 0);
                }

                // epilogue for this lane's col only
                float z = (sel4(A0, q) + sel4(A1, q))
                        + (sel4(A2, q) + sel4(A3, q));
                float e = __expf(2.0f * z);                     // inf-safe
                float r = __builtin_amdgcn_rcpf(e + 1.0f);      // 1/(e+1)
                hj = __builtin_fmaf(nsj2, r, term1);            // h+s*(tanh-h)
                hbuf[hb ^ 1][mycol] = (_Float16)hj;
                LGKM_BARRIER();
                hb ^= 1;
            }
            xv_cur = xv_nxt;
        }
    }

    out[(size_t)b * 256 + mycol] = hj;
}

extern "C" void kernel_launch(void* const* d_in, const int* in_sizes, int n_in,
                              void* d_out, int out_size, void* d_ws, size_t ws_size,
                              hipStream_t stream) {
    const float* x     = (const float*)d_in[0];
    const float* W_in  = (const float*)d_in[1];
    const float* b_in  = (const float*)d_in[2];
    const float* W_rec = (const float*)d_in[3];
    const float* b_rec = (const float*)d_in[4];
    const float* tau   = (const float*)d_in[5];
    const int*   numl  = (const int*)d_in[6];

    const int H = in_sizes[2];            // 256
    const int I = in_sizes[1] / H;        // 128
    const int B = out_size / H;           // 64
    const int T = in_sizes[0] / (B * I);  // 4096

    ltc_fused<<<B, 256, 0, stream>>>(x, W_in, b_in, W_rec, b_rec, tau,
                                     numl, (float*)d_out, T);
}